// Round 6
// baseline (1104.465 us; speedup 1.0000x reference)
//
#include <hip/hip_runtime.h>
#include <hip/hip_bf16.h>

typedef unsigned short ushort_t;
typedef __attribute__((ext_vector_type(8))) __bf16 bf16x8;
typedef __attribute__((ext_vector_type(4))) float f32x4;
typedef __attribute__((ext_vector_type(4))) unsigned int u32x4;

#define DEPTH 6
#define HEADS 12
#define DMODEL 768
#define FFDIM 3072
#define BATCH 2
#define SEQ 1024
#define ROWS (BATCH * SEQ)

static __device__ __forceinline__ ushort_t f2bf(float f) {
  unsigned u = __builtin_bit_cast(unsigned, f);
  u += 0x7fffu + ((u >> 16) & 1u);
  return (ushort_t)(u >> 16);
}

template <int N>
static __device__ __forceinline__ void wait_vmcnt() {
  if constexpr (N == 0) asm volatile("s_waitcnt vmcnt(0)" ::: "memory");
  else if constexpr (N == 3) asm volatile("s_waitcnt vmcnt(3)" ::: "memory");
  else if constexpr (N == 4) asm volatile("s_waitcnt vmcnt(4)" ::: "memory");
  else if constexpr (N == 6) asm volatile("s_waitcnt vmcnt(6)" ::: "memory");
  else if constexpr (N == 8) asm volatile("s_waitcnt vmcnt(8)" ::: "memory");
}

// ---------------------------------------------------------------------------
// GEMM: C[M,N] = A[M,K] @ Bt[N,K]^T, bf16 K-major, fp32 MFMA accum.
// 4-buffer BK=32 pipeline, 3 tiles in flight, counted vmcnt (T4):
//   prologue: stage(0,1,2)
//   loop t:  wait vmcnt(2L) [drain oldest tile only] ; s_barrier ;
//            stage(t+3) ; ds_read+MFMA on buf[t&3]
// LDS linear dest + XOR-swizzled global source (slot = kq4 ^ ((row>>1)&3))
// -> ds_read_b128 2-way (free). XCD-aware block swizzle (grids % 8 == 0).
// EPI: 0=qkv(q,k->qkvb, v->vt), 3=out-proj residual RMW,
//      4=ff1 bias+gelu bf16, 5=ff2 residual RMW
// ---------------------------------------------------------------------------
template <int MREP, int NREP, int EPI>
__global__ __launch_bounds__(256) void gemm_bt(
    const ushort_t* __restrict__ A, const ushort_t* __restrict__ Bt,
    int lda, int ldb, int K,
    void* __restrict__ out0, void* __restrict__ out1,
    const float* __restrict__ f0) {
  constexpr int BM = 32 * MREP;
  constexpr int BN = 32 * NREP;
  constexpr int CHA = BM / 64;  // 16-row chunks per wave (A)
  constexpr int CHB = BN / 64;
  constexpr int L = CHA + CHB;  // loads per wave per K-tile
  __shared__ ushort_t sA[4][BM * 32];
  __shared__ ushort_t sB[4][BN * 32];

  const int tid = threadIdx.x;
  const int lane = tid & 63;
  const int wid = tid >> 6;
  const int wm = wid >> 1, wn = wid & 1;

  // XCD-aware bijective block swizzle (total blocks divisible by 8)
  int bx, by;
  {
    const int nb = gridDim.x * gridDim.y;
    const int bid = blockIdx.y * gridDim.x + blockIdx.x;
    const int q = nb >> 3;
    const int swz = (bid & 7) * q + (bid >> 3);
    bx = swz % gridDim.x;
    by = swz / gridDim.x;
  }

  const ushort_t* Ab = A + (long)bx * BM * lda;
  const ushort_t* Bb = Bt + (long)by * BN * ldb;

  // staging: each global_load_lds covers 16 rows x 64B; source col swizzled
  const int srow = lane >> 2;                          // row within chunk
  const int scol = (((lane & 3) ^ ((lane >> 3) & 3))) * 8;

  f32x4 acc[MREP][NREP];
#pragma unroll
  for (int m = 0; m < MREP; ++m)
#pragma unroll
    for (int n = 0; n < NREP; ++n) acc[m][n] = (f32x4){0.f, 0.f, 0.f, 0.f};

  const int fr = lane & 15;
  const int kq4 = lane >> 4;

  auto stage_tile = [&](int buf, int t) {
    const int k0 = t * 32;
#pragma unroll
    for (int j = 0; j < CHA; ++j) {
      const int c = wid * CHA + j;
      const ushort_t* src = Ab + (long)(c * 16 + srow) * lda + k0 + scol;
      __builtin_amdgcn_global_load_lds(
          (const __attribute__((address_space(1))) void*)src,
          (__attribute__((address_space(3))) void*)&sA[buf][c * 512], 16, 0, 0);
    }
#pragma unroll
    for (int j = 0; j < CHB; ++j) {
      const int c = wid * CHB + j;
      const ushort_t* src = Bb + (long)(c * 16 + srow) * ldb + k0 + scol;
      __builtin_amdgcn_global_load_lds(
          (const __attribute__((address_space(1))) void*)src,
          (__attribute__((address_space(3))) void*)&sB[buf][c * 512], 16, 0, 0);
    }
  };

  auto compute_tile = [&](int buf) {
    bf16x8 af[MREP], bfr[NREP];
#pragma unroll
    for (int m = 0; m < MREP; ++m) {
      const int row = wm * (MREP * 16) + m * 16 + fr;
      const int ch = kq4 ^ ((row >> 1) & 3);
      af[m] = *(const bf16x8*)&sA[buf][row * 32 + ch * 8];
    }
#pragma unroll
    for (int n = 0; n < NREP; ++n) {
      const int row = wn * (NREP * 16) + n * 16 + fr;
      const int ch = kq4 ^ ((row >> 1) & 3);
      bfr[n] = *(const bf16x8*)&sB[buf][row * 32 + ch * 8];
    }
#pragma unroll
    for (int m = 0; m < MREP; ++m)
#pragma unroll
      for (int n = 0; n < NREP; ++n)
        acc[m][n] = __builtin_amdgcn_mfma_f32_16x16x32_bf16(
            af[m], bfr[n], acc[m][n], 0, 0, 0);
  };

  const int nt = K / 32;  // >= 24 for all call sites
  stage_tile(0, 0);
  stage_tile(1, 1);
  stage_tile(2, 2);
  for (int t = 0; t < nt - 2; ++t) {
    wait_vmcnt<2 * L>();
    __builtin_amdgcn_s_barrier();
    if (t + 3 < nt) stage_tile((t + 3) & 3, t + 3);
    compute_tile(t & 3);
  }
  wait_vmcnt<L>();
  __builtin_amdgcn_s_barrier();
  compute_tile((nt - 2) & 3);
  wait_vmcnt<0>();
  __builtin_amdgcn_s_barrier();
  compute_tile((nt - 1) & 3);

  const long grow0 = (long)bx * BM + wm * (MREP * 16);
  const long gcol0 = (long)by * BN + wn * (NREP * 16);
  const int rr = (lane >> 4) * 4;
  const int cc = lane & 15;

#pragma unroll
  for (int m = 0; m < MREP; ++m) {
#pragma unroll
    for (int n = 0; n < NREP; ++n) {
#pragma unroll
      for (int r = 0; r < 4; ++r) {
        long row = grow0 + m * 16 + rr + r;
        long col = gcol0 + n * 16 + cc;
        float c = acc[m][n][r];
        if (EPI == 0) {
          ushort_t bv = f2bf(c);
          if (col < 1536) {
            ((ushort_t*)out0)[row * 2304 + col] = bv;
          } else {  // V block -> V^T only
            long h = (col - 1536) >> 6, d = (col - 1536) & 63;
            long b = row >> 10, i = row & 1023;
            ((ushort_t*)out1)[(((b * HEADS) + h) * 64 + d) * 1024 + i] = bv;
          }
        } else if (EPI == 3) {
          long idx = row * DMODEL + col;
          ((float*)out0)[idx] += c + f0[col];
        } else if (EPI == 4) {
          float t = c + f0[col];
          float g = 0.5f * t * (1.0f + erff(t * 0.70710678118f));
          ((ushort_t*)out0)[row * FFDIM + col] = f2bf(g);
        } else if (EPI == 5) {
          long idx = row * DMODEL + col;
          ((float*)out0)[idx] += c + f0[col];
        }
      }
    }
  }
}

// ---------------------------------------------------------------------------
// Flash attention: QBLK=64, KVBLK=64. 4 waves, each owns 16 q-rows (full 64
// cols) -> row softmax reduces within 16-lane shfl groups only. Q in regs
// (A-frag layout). K/V double-buffered in LDS via swizzled global_load_lds.
// P -> swizzled LDS tile to convert C-layout to A-frag layout.
// grid: (SEQ/64, HEADS, BATCH)
// ---------------------------------------------------------------------------
__global__ __launch_bounds__(256) void flash_attn(
    const ushort_t* __restrict__ qkv,  // [ROWS][2304] (q at h*64, k at 768+h*64)
    const ushort_t* __restrict__ vt,   // [B*H*64][1024] V^T, rows d, cols j
    const float* __restrict__ rel,     // [H][1024][1024]
    ushort_t* __restrict__ o) {        // [ROWS][768]
  __shared__ ushort_t sK[2][64 * 64];
  __shared__ ushort_t sV[2][64 * 64];
  __shared__ ushort_t sP[64 * 64];

  const int tid = threadIdx.x;
  const int lane = tid & 63;
  const int wid = tid >> 6;
  const int h = blockIdx.y, b = blockIdx.z;
  const int q0 = blockIdx.x * 64;

  const int fr = lane & 15;
  const int kq4 = lane >> 4;
  const int rr = kq4 * 4;  // C-layout row base
  const int cc = fr;

  const int srow = lane >> 3;
  const int scol = ((lane & 7) ^ srow) * 8;

  // Q fragments in registers (row = wid*16+fr fixed per lane)
  const ushort_t* qbase =
      qkv + (size_t)(b * 1024 + q0 + wid * 16 + fr) * 2304 + h * 64;
  bf16x8 qreg[2];
  qreg[0] = *(const bf16x8*)&qbase[kq4 * 8];
  qreg[1] = *(const bf16x8*)&qbase[32 + kq4 * 8];

  const ushort_t* Kbase = qkv + (size_t)(b * 1024) * 2304 + 768 + h * 64;
  const ushort_t* Vbase = vt + (size_t)((b * HEADS + h) * 64) * 1024;

  f32x4 acc_o[4];
  float m_run[4], l_run[4];
#pragma unroll
  for (int n = 0; n < 4; ++n) acc_o[n] = (f32x4){0.f, 0.f, 0.f, 0.f};
#pragma unroll
  for (int r = 0; r < 4; ++r) { m_run[r] = -1e30f; l_run[r] = 0.f; }

  auto stage_kv = [&](int buf, int t) {
#pragma unroll
    for (int j = 0; j < 2; ++j) {
      const int c = wid * 2 + j;
      const ushort_t* src = Kbase + (size_t)(t * 64 + c * 8 + srow) * 2304 + scol;
      __builtin_amdgcn_global_load_lds(
          (const __attribute__((address_space(1))) void*)src,
          (__attribute__((address_space(3))) void*)&sK[buf][c * 512], 16, 0, 0);
    }
#pragma unroll
    for (int j = 0; j < 2; ++j) {
      const int c = wid * 2 + j;
      const ushort_t* src = Vbase + (size_t)(c * 8 + srow) * 1024 + t * 64 + scol;
      __builtin_amdgcn_global_load_lds(
          (const __attribute__((address_space(1))) void*)src,
          (__attribute__((address_space(3))) void*)&sV[buf][c * 512], 16, 0, 0);
    }
  };

  stage_kv(0, 0);
  for (int t = 0; t < 16; ++t) {
    const int cur = t & 1;
    asm volatile("s_waitcnt vmcnt(0)" ::: "memory");
    __builtin_amdgcn_s_barrier();

    // rel_bias for this tile
    float bias[4][4];
    {
      const float* rb = rel + ((size_t)h << 20) +
                        (size_t)(q0 + wid * 16 + rr) * 1024 + t * 64 + cc;
#pragma unroll
      for (int n = 0; n < 4; ++n)
#pragma unroll
        for (int r = 0; r < 4; ++r) bias[n][r] = rb[(size_t)r * 1024 + n * 16];
    }

    if (t + 1 < 16) stage_kv(cur ^ 1, t + 1);

    // S = Q @ K^T
    f32x4 s[4];
#pragma unroll
    for (int n = 0; n < 4; ++n) s[n] = (f32x4){0.f, 0.f, 0.f, 0.f};
#pragma unroll
    for (int kk = 0; kk < 2; ++kk) {
#pragma unroll
      for (int n = 0; n < 4; ++n) {
        const int row = n * 16 + fr;
        const int ch = (kk * 4 + kq4) ^ (row & 7);
        bf16x8 kf = *(const bf16x8*)&sK[cur][row * 64 + ch * 8];
        s[n] =
            __builtin_amdgcn_mfma_f32_16x16x32_bf16(qreg[kk], kf, s[n], 0, 0, 0);
      }
    }

    // scale + bias, per-row tile max
    float mr[4];
#pragma unroll
    for (int r = 0; r < 4; ++r) mr[r] = -1e30f;
#pragma unroll
    for (int n = 0; n < 4; ++n)
#pragma unroll
      for (int r = 0; r < 4; ++r) {
        float v = s[n][r] * 0.125f + bias[n][r];
        s[n][r] = v;
        mr[r] = fmaxf(mr[r], v);
      }
#pragma unroll
    for (int o_ = 1; o_ < 16; o_ <<= 1)
#pragma unroll
      for (int r = 0; r < 4; ++r) mr[r] = fmaxf(mr[r], __shfl_xor(mr[r], o_));

    float escale[4], psum[4];
#pragma unroll
    for (int r = 0; r < 4; ++r) {
      float mn = fmaxf(m_run[r], mr[r]);
      escale[r] = __expf(m_run[r] - mn);
      m_run[r] = mn;
      psum[r] = 0.f;
    }
    // P = exp(S - m), write to swizzled sP
#pragma unroll
    for (int n = 0; n < 4; ++n)
#pragma unroll
      for (int r = 0; r < 4; ++r) {
        float p = __expf(s[n][r] - m_run[r]);
        psum[r] += p;
        const int prow = wid * 16 + rr + r;
        const int pcol = n * 16 + cc;
        sP[prow * 64 + (((pcol >> 3) ^ (prow & 7)) << 3) + (pcol & 7)] = f2bf(p);
      }
#pragma unroll
    for (int o_ = 1; o_ < 16; o_ <<= 1)
#pragma unroll
      for (int r = 0; r < 4; ++r) psum[r] += __shfl_xor(psum[r], o_);
#pragma unroll
    for (int r = 0; r < 4; ++r) l_run[r] = l_run[r] * escale[r] + psum[r];

    asm volatile("s_waitcnt lgkmcnt(0)" ::: "memory");
    __builtin_amdgcn_s_barrier();

    // O = O*escale + P @ V
#pragma unroll
    for (int n = 0; n < 4; ++n)
#pragma unroll
      for (int r = 0; r < 4; ++r) acc_o[n][r] *= escale[r];
#pragma unroll
    for (int kk = 0; kk < 2; ++kk) {
      const int prow = wid * 16 + fr;
      const int pch = (kk * 4 + kq4) ^ (prow & 7);
      bf16x8 pf = *(const bf16x8*)&sP[prow * 64 + pch * 8];
#pragma unroll
      for (int n = 0; n < 4; ++n) {
        const int vrow = n * 16 + fr;
        const int vch = (kk * 4 + kq4) ^ (vrow & 7);
        bf16x8 vf = *(const bf16x8*)&sV[cur][vrow * 64 + vch * 8];
        acc_o[n] =
            __builtin_amdgcn_mfma_f32_16x16x32_bf16(pf, vf, acc_o[n], 0, 0, 0);
      }
    }
  }

  ushort_t* ob = o + (size_t)(b * 1024 + q0 + wid * 16) * 768 + h * 64;
#pragma unroll
  for (int r = 0; r < 4; ++r) {
    const float rinv = 1.f / l_run[r];
#pragma unroll
    for (int n = 0; n < 4; ++n)
      ob[(size_t)(rr + r) * 768 + n * 16 + cc] = f2bf(acc_o[n][r] * rinv);
  }
}

// ---------------------------------------------------------------------------
// Transpose + cast fp32 [R,C] -> bf16 [C,R], per-layer via blockIdx.z
// ---------------------------------------------------------------------------
__global__ __launch_bounds__(256) void transpose_cast(
    const float* __restrict__ in, ushort_t* __restrict__ out, int R, int C) {
  __shared__ float t[32][33];
  const float* ip = in + (long)blockIdx.z * R * C;
  ushort_t* op = out + (long)blockIdx.z * R * C;
  int c0 = blockIdx.x * 32, r0 = blockIdx.y * 32;
  int tx = threadIdx.x;
  for (int i = threadIdx.y; i < 32; i += 8)
    t[i][tx] = ip[(long)(r0 + i) * C + c0 + tx];
  __syncthreads();
  for (int i = threadIdx.y; i < 32; i += 8)
    op[(long)(c0 + i) * R + r0 + tx] = f2bf(t[tx][i]);
}

// ---------------------------------------------------------------------------
// LayerNorm over D=768; block per row; out bf16 (flag=0) or fp32 (flag=1)
// ---------------------------------------------------------------------------
__global__ __launch_bounds__(256) void ln_kernel(
    const float* __restrict__ x, const float* __restrict__ g,
    const float* __restrict__ b, void* __restrict__ out, int out_f32) {
  int row = blockIdx.x;
  int tid = threadIdx.x;
  int lane = tid & 63, wid = tid >> 6;
  const float* xr = x + (long)row * DMODEL;
  float v0 = xr[tid], v1 = xr[tid + 256], v2 = xr[tid + 512];
  float s = v0 + v1 + v2;
  __shared__ float red[8];
  for (int o = 32; o; o >>= 1) s += __shfl_xor(s, o);
  if (!lane) red[wid] = s;
  __syncthreads();
  float mean = (red[0] + red[1] + red[2] + red[3]) * (1.f / 768.f);
  float d0 = v0 - mean, d1 = v1 - mean, d2 = v2 - mean;
  float q = d0 * d0 + d1 * d1 + d2 * d2;
  for (int o = 32; o; o >>= 1) q += __shfl_xor(q, o);
  if (!lane) red[4 + wid] = q;
  __syncthreads();
  float var = (red[4] + red[5] + red[6] + red[7]) * (1.f / 768.f);
  float rs = rsqrtf(var + 1e-5f);
  float y0 = d0 * rs * g[tid] + b[tid];
  float y1 = d1 * rs * g[tid + 256] + b[tid + 256];
  float y2 = d2 * rs * g[tid + 512] + b[tid + 512];
  if (out_f32) {
    float* o_ = (float*)out + (long)row * DMODEL;
    o_[tid] = y0; o_[tid + 256] = y1; o_[tid + 512] = y2;
  } else {
    ushort_t* o_ = (ushort_t*)out + (long)row * DMODEL;
    o_[tid] = f2bf(y0); o_[tid + 256] = f2bf(y1); o_[tid + 512] = f2bf(y2);
  }
}

// ---------------------------------------------------------------------------
// Feature output: out[b, c, n] = x[b, n, c]
// ---------------------------------------------------------------------------
__global__ __launch_bounds__(256) void feat_kernel(const float* __restrict__ x,
                                                   float* __restrict__ out) {
  __shared__ float t[32][33];
  const float* xp = x + (long)blockIdx.z * SEQ * DMODEL;
  float* op = out + (long)blockIdx.z * DMODEL * SEQ;
  int n0 = blockIdx.x * 32, c0 = blockIdx.y * 32;
  int tx = threadIdx.x;
  for (int i = threadIdx.y; i < 32; i += 8)
    t[i][tx] = xp[(long)(n0 + i) * DMODEL + c0 + tx];
  __syncthreads();
  for (int i = threadIdx.y; i < 32; i += 8)
    op[(long)(c0 + i) * SEQ + n0 + tx] = t[tx][i];
}

// ---------------------------------------------------------------------------
extern "C" void kernel_launch(void* const* d_in, const int* in_sizes, int n_in,
                              void* d_out, int out_size, void* d_ws,
                              size_t ws_size, hipStream_t stream) {
  const float* x_in   = (const float*)d_in[0];
  const float* rel    = (const float*)d_in[1];
  const float* ln1_g  = (const float*)d_in[2];
  const float* ln1_b  = (const float*)d_in[3];
  const float* qkv_w  = (const float*)d_in[4];
  const float* out_w  = (const float*)d_in[5];
  const float* out_b  = (const float*)d_in[6];
  const float* ln2_g  = (const float*)d_in[7];
  const float* ln2_b  = (const float*)d_in[8];
  const float* ff1_w  = (const float*)d_in[9];
  const float* ff1_b  = (const float*)d_in[10];
  const float* ff2_w  = (const float*)d_in[11];
  const float* ff2_b  = (const float*)d_in[12];
  const float* lnf_g  = (const float*)d_in[13];
  const float* lnf_b  = (const float*)d_in[14];
  float* out = (float*)d_out;

  char* w = (char*)d_ws;
  ushort_t* wq_t = (ushort_t*)w; w += (size_t)DEPTH * 2304 * 768 * 2;
  ushort_t* wo_t = (ushort_t*)w; w += (size_t)DEPTH * 768 * 768 * 2;
  ushort_t* wf1_t = (ushort_t*)w; w += (size_t)DEPTH * 3072 * 768 * 2;
  ushort_t* wf2_t = (ushort_t*)w; w += (size_t)DEPTH * 768 * 3072 * 2;
  float* xb = (float*)w; w += (size_t)ROWS * DMODEL * 4;
  ushort_t* hb = (ushort_t*)w; w += (size_t)ROWS * DMODEL * 2;
  ushort_t* qkvb = (ushort_t*)w; w += (size_t)ROWS * 2304 * 2;
  ushort_t* vt = (ushort_t*)w; w += (size_t)BATCH * HEADS * 64 * 1024 * 2;
  ushort_t* ob = (ushort_t*)w; w += (size_t)ROWS * DMODEL * 2;
  ushort_t* ffb = (ushort_t*)w; w += (size_t)ROWS * FFDIM * 2;

  dim3 tb(32, 8);
  // weight prep: fp32 [K,N] -> bf16 [N,K]
  transpose_cast<<<dim3(2304 / 32, 768 / 32, DEPTH), tb, 0, stream>>>(
      qkv_w, wq_t, 768, 2304);
  transpose_cast<<<dim3(768 / 32, 768 / 32, DEPTH), tb, 0, stream>>>(
      out_w, wo_t, 768, 768);
  transpose_cast<<<dim3(3072 / 32, 768 / 32, DEPTH), tb, 0, stream>>>(
      ff1_w, wf1_t, 768, 3072);
  transpose_cast<<<dim3(768 / 32, 3072 / 32, DEPTH), tb, 0, stream>>>(
      ff2_w, wf2_t, 3072, 768);

  hipMemcpyAsync(xb, x_in, (size_t)ROWS * DMODEL * 4, hipMemcpyDeviceToDevice,
                 stream);

  for (int i = 0; i < DEPTH; ++i) {
    // attention block
    ln_kernel<<<ROWS, 256, 0, stream>>>(xb, ln1_g + i * 768, ln1_b + i * 768,
                                        hb, 0);
    gemm_bt<4, 4, 0><<<dim3(16, 18), 256, 0, stream>>>(
        hb, wq_t + (size_t)i * 2304 * 768, 768, 768, 768, qkvb, vt, nullptr);
    flash_attn<<<dim3(16, HEADS, BATCH), 256, 0, stream>>>(qkvb, vt, rel, ob);
    gemm_bt<4, 2, 3><<<dim3(16, 12), 256, 0, stream>>>(
        ob, wo_t + (size_t)i * 768 * 768, 768, 768, 768, xb, nullptr,
        out_b + i * 768);
    // FFN block
    ln_kernel<<<ROWS, 256, 0, stream>>>(xb, ln2_g + i * 768, ln2_b + i * 768,
                                        hb, 0);
    gemm_bt<4, 4, 4><<<dim3(16, 24), 256, 0, stream>>>(
        hb, wf1_t + (size_t)i * 3072 * 768, 768, 768, 768, ffb, nullptr,
        ff1_b + i * 3072);
    gemm_bt<4, 2, 5><<<dim3(16, 12), 256, 0, stream>>>(
        ffb, wf2_t + (size_t)i * 768 * 3072, 3072, 3072, 3072, xb, nullptr,
        ff2_b + i * 768);
    if (i == 2)
      feat_kernel<<<dim3(32, 24, 2), tb, 0, stream>>>(xb, out + 1572864);
    if (i == 5)
      feat_kernel<<<dim3(32, 24, 2), tb, 0, stream>>>(xb, out + 2 * 1572864);
  }
  ln_kernel<<<ROWS, 256, 0, stream>>>(xb, lnf_g, lnf_b, out, 1);
}

// Round 7
// 927.240 us; speedup vs baseline: 1.1911x; 1.1911x over previous
//
#include <hip/hip_runtime.h>
#include <hip/hip_bf16.h>

typedef unsigned short ushort_t;
typedef __attribute__((ext_vector_type(8))) __bf16 bf16x8;
typedef __attribute__((ext_vector_type(4))) float f32x4;
typedef __attribute__((ext_vector_type(4))) unsigned int u32x4;

#define DEPTH 6
#define HEADS 12
#define DMODEL 768
#define FFDIM 3072
#define BATCH 2
#define SEQ 1024
#define ROWS (BATCH * SEQ)

static __device__ __forceinline__ ushort_t f2bf(float f) {
  unsigned u = __builtin_bit_cast(unsigned, f);
  u += 0x7fffu + ((u >> 16) & 1u);
  return (ushort_t)(u >> 16);
}

// ---------------------------------------------------------------------------
// GEMM: C[M,N] = A[M,K] @ Bt[N,K]^T, bf16 K-major, fp32 MFMA accum.
// Round-5 2-phase structure (best measured): per K-tile (BK=64)
//   { vmcnt(0); s_barrier; stage(t+1) -> buf^1; ds_read+MFMA on buf }
// SMALL TILES for TLP: grid is 3-6x CU count, 4-6 blocks/CU by LDS ->
// implicit wave-level overlap does the latency hiding (m114 regime).
// LDS linear dest + XOR-swizzled global source; swizzled ds_read_b128.
// XCD-aware bijective block swizzle (all grids divisible by 8).
// EPI: 0=qkv(q,k->qkvb, v->vt), 3=out-proj residual RMW,
//      4=ff1 bias+gelu bf16, 5=ff2 residual RMW
// ---------------------------------------------------------------------------
template <int MREP, int NREP, int EPI>
__global__ __launch_bounds__(256) void gemm_bt(
    const ushort_t* __restrict__ A, const ushort_t* __restrict__ Bt,
    int lda, int ldb, int K,
    void* __restrict__ out0, void* __restrict__ out1,
    const float* __restrict__ f0) {
  constexpr int BM = 32 * MREP;
  constexpr int BN = 32 * NREP;
  constexpr int CHA = BM / 32;  // 8-row staging chunks per wave
  constexpr int CHB = BN / 32;
  __shared__ ushort_t sA[2][BM * 64];
  __shared__ ushort_t sB[2][BN * 64];

  const int tid = threadIdx.x;
  const int lane = tid & 63;
  const int wid = tid >> 6;
  const int wm = wid >> 1, wn = wid & 1;

  // XCD-aware bijective block swizzle (total blocks divisible by 8)
  int bx, by;
  {
    const int nb = gridDim.x * gridDim.y;
    const int bid = blockIdx.y * gridDim.x + blockIdx.x;
    const int q = nb >> 3;
    const int swz = (bid & 7) * q + (bid >> 3);
    bx = swz % gridDim.x;
    by = swz / gridDim.x;
  }

  const ushort_t* Ab = A + (long)bx * BM * lda;
  const ushort_t* Bb = Bt + (long)by * BN * ldb;

  const int srow = lane >> 3;                // row within 8-row chunk
  const int scol = ((lane & 7) ^ srow) * 8;  // swizzled source col (elems)

  f32x4 acc[MREP][NREP];
#pragma unroll
  for (int m = 0; m < MREP; ++m)
#pragma unroll
    for (int n = 0; n < NREP; ++n) acc[m][n] = (f32x4){0.f, 0.f, 0.f, 0.f};

  const int fr = lane & 15;
  const int kq4 = lane >> 4;

  auto stage_tile = [&](int buf, int t) {
    const int k0 = t * 64;
#pragma unroll
    for (int j = 0; j < CHA; ++j) {
      const int c = wid * CHA + j;
      const ushort_t* src = Ab + (long)(c * 8 + srow) * lda + k0 + scol;
      __builtin_amdgcn_global_load_lds(
          (const __attribute__((address_space(1))) void*)src,
          (__attribute__((address_space(3))) void*)&sA[buf][c * 512], 16, 0, 0);
    }
#pragma unroll
    for (int j = 0; j < CHB; ++j) {
      const int c = wid * CHB + j;
      const ushort_t* src = Bb + (long)(c * 8 + srow) * ldb + k0 + scol;
      __builtin_amdgcn_global_load_lds(
          (const __attribute__((address_space(1))) void*)src,
          (__attribute__((address_space(3))) void*)&sB[buf][c * 512], 16, 0, 0);
    }
  };

  const int nt = K / 64;
  stage_tile(0, 0);
  for (int t = 0; t < nt; ++t) {
    const int cur = t & 1;
    asm volatile("s_waitcnt vmcnt(0)" ::: "memory");
    __builtin_amdgcn_s_barrier();
    if (t + 1 < nt) stage_tile(cur ^ 1, t + 1);
#pragma unroll
    for (int kk = 0; kk < 2; ++kk) {
      bf16x8 af[MREP], bfr[NREP];
#pragma unroll
      for (int m = 0; m < MREP; ++m) {
        const int row = wm * (MREP * 16) + m * 16 + fr;
        const int ch = (kk * 4 + kq4) ^ (row & 7);
        af[m] = *(const bf16x8*)&sA[cur][row * 64 + ch * 8];
      }
#pragma unroll
      for (int n = 0; n < NREP; ++n) {
        const int row = wn * (NREP * 16) + n * 16 + fr;
        const int ch = (kk * 4 + kq4) ^ (row & 7);
        bfr[n] = *(const bf16x8*)&sB[cur][row * 64 + ch * 8];
      }
#pragma unroll
      for (int m = 0; m < MREP; ++m)
#pragma unroll
        for (int n = 0; n < NREP; ++n)
          acc[m][n] = __builtin_amdgcn_mfma_f32_16x16x32_bf16(
              af[m], bfr[n], acc[m][n], 0, 0, 0);
    }
  }

  const long grow0 = (long)bx * BM + wm * (MREP * 16);
  const long gcol0 = (long)by * BN + wn * (NREP * 16);
  const int rr = (lane >> 4) * 4;
  const int cc = lane & 15;

#pragma unroll
  for (int m = 0; m < MREP; ++m) {
#pragma unroll
    for (int n = 0; n < NREP; ++n) {
#pragma unroll
      for (int r = 0; r < 4; ++r) {
        long row = grow0 + m * 16 + rr + r;
        long col = gcol0 + n * 16 + cc;
        float c = acc[m][n][r];
        if (EPI == 0) {
          ushort_t bv = f2bf(c);
          if (col < 1536) {
            ((ushort_t*)out0)[row * 2304 + col] = bv;
          } else {  // V block -> V^T only
            long h = (col - 1536) >> 6, d = (col - 1536) & 63;
            long b = row >> 10, i = row & 1023;
            ((ushort_t*)out1)[(((b * HEADS) + h) * 64 + d) * 1024 + i] = bv;
          }
        } else if (EPI == 3) {
          long idx = row * DMODEL + col;
          ((float*)out0)[idx] += c + f0[col];
        } else if (EPI == 4) {
          float t = c + f0[col];
          float g = 0.5f * t * (1.0f + erff(t * 0.70710678118f));
          ((ushort_t*)out0)[row * FFDIM + col] = f2bf(g);
        } else if (EPI == 5) {
          long idx = row * DMODEL + col;
          ((float*)out0)[idx] += c + f0[col];
        }
      }
    }
  }
}

// ---------------------------------------------------------------------------
// Flash attention: QBLK=64, KVBLK=64. 4 waves, each owns 16 q-rows (full 64
// cols) -> row softmax reduces within 16-lane shfl groups only. Q in regs
// (A-frag layout). K/V double-buffered in LDS via swizzled global_load_lds.
// P -> swizzled LDS tile to convert C-layout to A-frag layout.
// grid: (SEQ/64, HEADS, BATCH)
// ---------------------------------------------------------------------------
__global__ __launch_bounds__(256) void flash_attn(
    const ushort_t* __restrict__ qkv,  // [ROWS][2304] (q at h*64, k at 768+h*64)
    const ushort_t* __restrict__ vt,   // [B*H*64][1024] V^T, rows d, cols j
    const float* __restrict__ rel,     // [H][1024][1024]
    ushort_t* __restrict__ o) {        // [ROWS][768]
  __shared__ ushort_t sK[2][64 * 64];
  __shared__ ushort_t sV[2][64 * 64];
  __shared__ ushort_t sP[64 * 64];

  const int tid = threadIdx.x;
  const int lane = tid & 63;
  const int wid = tid >> 6;
  const int h = blockIdx.y, b = blockIdx.z;
  const int q0 = blockIdx.x * 64;

  const int fr = lane & 15;
  const int kq4 = lane >> 4;
  const int rr = kq4 * 4;  // C-layout row base
  const int cc = fr;

  const int srow = lane >> 3;
  const int scol = ((lane & 7) ^ srow) * 8;

  // Q fragments in registers (row = wid*16+fr fixed per lane)
  const ushort_t* qbase =
      qkv + (size_t)(b * 1024 + q0 + wid * 16 + fr) * 2304 + h * 64;
  bf16x8 qreg[2];
  qreg[0] = *(const bf16x8*)&qbase[kq4 * 8];
  qreg[1] = *(const bf16x8*)&qbase[32 + kq4 * 8];

  const ushort_t* Kbase = qkv + (size_t)(b * 1024) * 2304 + 768 + h * 64;
  const ushort_t* Vbase = vt + (size_t)((b * HEADS + h) * 64) * 1024;

  f32x4 acc_o[4];
  float m_run[4], l_run[4];
#pragma unroll
  for (int n = 0; n < 4; ++n) acc_o[n] = (f32x4){0.f, 0.f, 0.f, 0.f};
#pragma unroll
  for (int r = 0; r < 4; ++r) { m_run[r] = -1e30f; l_run[r] = 0.f; }

  auto stage_kv = [&](int buf, int t) {
#pragma unroll
    for (int j = 0; j < 2; ++j) {
      const int c = wid * 2 + j;
      const ushort_t* src = Kbase + (size_t)(t * 64 + c * 8 + srow) * 2304 + scol;
      __builtin_amdgcn_global_load_lds(
          (const __attribute__((address_space(1))) void*)src,
          (__attribute__((address_space(3))) void*)&sK[buf][c * 512], 16, 0, 0);
    }
#pragma unroll
    for (int j = 0; j < 2; ++j) {
      const int c = wid * 2 + j;
      const ushort_t* src = Vbase + (size_t)(c * 8 + srow) * 1024 + t * 64 + scol;
      __builtin_amdgcn_global_load_lds(
          (const __attribute__((address_space(1))) void*)src,
          (__attribute__((address_space(3))) void*)&sV[buf][c * 512], 16, 0, 0);
    }
  };

  stage_kv(0, 0);
  for (int t = 0; t < 16; ++t) {
    const int cur = t & 1;
    asm volatile("s_waitcnt vmcnt(0)" ::: "memory");
    __builtin_amdgcn_s_barrier();

    // rel_bias for this tile
    float bias[4][4];
    {
      const float* rb = rel + ((size_t)h << 20) +
                        (size_t)(q0 + wid * 16 + rr) * 1024 + t * 64 + cc;
#pragma unroll
      for (int n = 0; n < 4; ++n)
#pragma unroll
        for (int r = 0; r < 4; ++r) bias[n][r] = rb[(size_t)r * 1024 + n * 16];
    }

    if (t + 1 < 16) stage_kv(cur ^ 1, t + 1);

    // S = Q @ K^T
    f32x4 s[4];
#pragma unroll
    for (int n = 0; n < 4; ++n) s[n] = (f32x4){0.f, 0.f, 0.f, 0.f};
#pragma unroll
    for (int kk = 0; kk < 2; ++kk) {
#pragma unroll
      for (int n = 0; n < 4; ++n) {
        const int row = n * 16 + fr;
        const int ch = (kk * 4 + kq4) ^ (row & 7);
        bf16x8 kf = *(const bf16x8*)&sK[cur][row * 64 + ch * 8];
        s[n] =
            __builtin_amdgcn_mfma_f32_16x16x32_bf16(qreg[kk], kf, s[n], 0, 0, 0);
      }
    }

    // scale + bias, per-row tile max
    float mr[4];
#pragma unroll
    for (int r = 0; r < 4; ++r) mr[r] = -1e30f;
#pragma unroll
    for (int n = 0; n < 4; ++n)
#pragma unroll
      for (int r = 0; r < 4; ++r) {
        float v = s[n][r] * 0.125f + bias[n][r];
        s[n][r] = v;
        mr[r] = fmaxf(mr[r], v);
      }
#pragma unroll
    for (int o_ = 1; o_ < 16; o_ <<= 1)
#pragma unroll
      for (int r = 0; r < 4; ++r) mr[r] = fmaxf(mr[r], __shfl_xor(mr[r], o_));

    float escale[4], psum[4];
#pragma unroll
    for (int r = 0; r < 4; ++r) {
      float mn = fmaxf(m_run[r], mr[r]);
      escale[r] = __expf(m_run[r] - mn);
      m_run[r] = mn;
      psum[r] = 0.f;
    }
    // P = exp(S - m), write to swizzled sP
#pragma unroll
    for (int n = 0; n < 4; ++n)
#pragma unroll
      for (int r = 0; r < 4; ++r) {
        float p = __expf(s[n][r] - m_run[r]);
        psum[r] += p;
        const int prow = wid * 16 + rr + r;
        const int pcol = n * 16 + cc;
        sP[prow * 64 + (((pcol >> 3) ^ (prow & 7)) << 3) + (pcol & 7)] = f2bf(p);
      }
#pragma unroll
    for (int o_ = 1; o_ < 16; o_ <<= 1)
#pragma unroll
      for (int r = 0; r < 4; ++r) psum[r] += __shfl_xor(psum[r], o_);
#pragma unroll
    for (int r = 0; r < 4; ++r) l_run[r] = l_run[r] * escale[r] + psum[r];

    asm volatile("s_waitcnt lgkmcnt(0)" ::: "memory");
    __builtin_amdgcn_s_barrier();

    // O = O*escale + P @ V
#pragma unroll
    for (int n = 0; n < 4; ++n)
#pragma unroll
      for (int r = 0; r < 4; ++r) acc_o[n][r] *= escale[r];
#pragma unroll
    for (int kk = 0; kk < 2; ++kk) {
      const int prow = wid * 16 + fr;
      const int pch = (kk * 4 + kq4) ^ (prow & 7);
      bf16x8 pf = *(const bf16x8*)&sP[prow * 64 + pch * 8];
#pragma unroll
      for (int n = 0; n < 4; ++n) {
        const int vrow = n * 16 + fr;
        const int vch = (kk * 4 + kq4) ^ (vrow & 7);
        bf16x8 vf = *(const bf16x8*)&sV[cur][vrow * 64 + vch * 8];
        acc_o[n] =
            __builtin_amdgcn_mfma_f32_16x16x32_bf16(pf, vf, acc_o[n], 0, 0, 0);
      }
    }
  }

  ushort_t* ob = o + (size_t)(b * 1024 + q0 + wid * 16) * 768 + h * 64;
#pragma unroll
  for (int r = 0; r < 4; ++r) {
    const float rinv = 1.f / l_run[r];
#pragma unroll
    for (int n = 0; n < 4; ++n)
      ob[(size_t)(rr + r) * 768 + n * 16 + cc] = f2bf(acc_o[n][r] * rinv);
  }
}

// ---------------------------------------------------------------------------
// Transpose + cast fp32 [R,C] -> bf16 [C,R], per-layer via blockIdx.z
// ---------------------------------------------------------------------------
__global__ __launch_bounds__(256) void transpose_cast(
    const float* __restrict__ in, ushort_t* __restrict__ out, int R, int C) {
  __shared__ float t[32][33];
  const float* ip = in + (long)blockIdx.z * R * C;
  ushort_t* op = out + (long)blockIdx.z * R * C;
  int c0 = blockIdx.x * 32, r0 = blockIdx.y * 32;
  int tx = threadIdx.x;
  for (int i = threadIdx.y; i < 32; i += 8)
    t[i][tx] = ip[(long)(r0 + i) * C + c0 + tx];
  __syncthreads();
  for (int i = threadIdx.y; i < 32; i += 8)
    op[(long)(c0 + i) * R + r0 + tx] = f2bf(t[tx][i]);
}

// ---------------------------------------------------------------------------
// LayerNorm over D=768; block per row; out bf16 (flag=0) or fp32 (flag=1)
// ---------------------------------------------------------------------------
__global__ __launch_bounds__(256) void ln_kernel(
    const float* __restrict__ x, const float* __restrict__ g,
    const float* __restrict__ b, void* __restrict__ out, int out_f32) {
  int row = blockIdx.x;
  int tid = threadIdx.x;
  int lane = tid & 63, wid = tid >> 6;
  const float* xr = x + (long)row * DMODEL;
  float v0 = xr[tid], v1 = xr[tid + 256], v2 = xr[tid + 512];
  float s = v0 + v1 + v2;
  __shared__ float red[8];
  for (int o = 32; o; o >>= 1) s += __shfl_xor(s, o);
  if (!lane) red[wid] = s;
  __syncthreads();
  float mean = (red[0] + red[1] + red[2] + red[3]) * (1.f / 768.f);
  float d0 = v0 - mean, d1 = v1 - mean, d2 = v2 - mean;
  float q = d0 * d0 + d1 * d1 + d2 * d2;
  for (int o = 32; o; o >>= 1) q += __shfl_xor(q, o);
  if (!lane) red[4 + wid] = q;
  __syncthreads();
  float var = (red[4] + red[5] + red[6] + red[7]) * (1.f / 768.f);
  float rs = rsqrtf(var + 1e-5f);
  float y0 = d0 * rs * g[tid] + b[tid];
  float y1 = d1 * rs * g[tid + 256] + b[tid + 256];
  float y2 = d2 * rs * g[tid + 512] + b[tid + 512];
  if (out_f32) {
    float* o_ = (float*)out + (long)row * DMODEL;
    o_[tid] = y0; o_[tid + 256] = y1; o_[tid + 512] = y2;
  } else {
    ushort_t* o_ = (ushort_t*)out + (long)row * DMODEL;
    o_[tid] = f2bf(y0); o_[tid + 256] = f2bf(y1); o_[tid + 512] = f2bf(y2);
  }
}

// ---------------------------------------------------------------------------
// Feature output: out[b, c, n] = x[b, n, c]
// ---------------------------------------------------------------------------
__global__ __launch_bounds__(256) void feat_kernel(const float* __restrict__ x,
                                                   float* __restrict__ out) {
  __shared__ float t[32][33];
  const float* xp = x + (long)blockIdx.z * SEQ * DMODEL;
  float* op = out + (long)blockIdx.z * DMODEL * SEQ;
  int n0 = blockIdx.x * 32, c0 = blockIdx.y * 32;
  int tx = threadIdx.x;
  for (int i = threadIdx.y; i < 32; i += 8)
    t[i][tx] = xp[(long)(n0 + i) * DMODEL + c0 + tx];
  __syncthreads();
  for (int i = threadIdx.y; i < 32; i += 8)
    op[(long)(c0 + i) * SEQ + n0 + tx] = t[tx][i];
}

// ---------------------------------------------------------------------------
extern "C" void kernel_launch(void* const* d_in, const int* in_sizes, int n_in,
                              void* d_out, int out_size, void* d_ws,
                              size_t ws_size, hipStream_t stream) {
  const float* x_in   = (const float*)d_in[0];
  const float* rel    = (const float*)d_in[1];
  const float* ln1_g  = (const float*)d_in[2];
  const float* ln1_b  = (const float*)d_in[3];
  const float* qkv_w  = (const float*)d_in[4];
  const float* out_w  = (const float*)d_in[5];
  const float* out_b  = (const float*)d_in[6];
  const float* ln2_g  = (const float*)d_in[7];
  const float* ln2_b  = (const float*)d_in[8];
  const float* ff1_w  = (const float*)d_in[9];
  const float* ff1_b  = (const float*)d_in[10];
  const float* ff2_w  = (const float*)d_in[11];
  const float* ff2_b  = (const float*)d_in[12];
  const float* lnf_g  = (const float*)d_in[13];
  const float* lnf_b  = (const float*)d_in[14];
  float* out = (float*)d_out;

  char* w = (char*)d_ws;
  ushort_t* wq_t = (ushort_t*)w; w += (size_t)DEPTH * 2304 * 768 * 2;
  ushort_t* wo_t = (ushort_t*)w; w += (size_t)DEPTH * 768 * 768 * 2;
  ushort_t* wf1_t = (ushort_t*)w; w += (size_t)DEPTH * 3072 * 768 * 2;
  ushort_t* wf2_t = (ushort_t*)w; w += (size_t)DEPTH * 768 * 3072 * 2;
  float* xb = (float*)w; w += (size_t)ROWS * DMODEL * 4;
  ushort_t* hb = (ushort_t*)w; w += (size_t)ROWS * DMODEL * 2;
  ushort_t* qkvb = (ushort_t*)w; w += (size_t)ROWS * 2304 * 2;
  ushort_t* vt = (ushort_t*)w; w += (size_t)BATCH * HEADS * 64 * 1024 * 2;
  ushort_t* ob = (ushort_t*)w; w += (size_t)ROWS * DMODEL * 2;
  ushort_t* ffb = (ushort_t*)w; w += (size_t)ROWS * FFDIM * 2;

  dim3 tb(32, 8);
  // weight prep: fp32 [K,N] -> bf16 [N,K]
  transpose_cast<<<dim3(2304 / 32, 768 / 32, DEPTH), tb, 0, stream>>>(
      qkv_w, wq_t, 768, 2304);
  transpose_cast<<<dim3(768 / 32, 768 / 32, DEPTH), tb, 0, stream>>>(
      out_w, wo_t, 768, 768);
  transpose_cast<<<dim3(3072 / 32, 768 / 32, DEPTH), tb, 0, stream>>>(
      ff1_w, wf1_t, 768, 3072);
  transpose_cast<<<dim3(768 / 32, 3072 / 32, DEPTH), tb, 0, stream>>>(
      ff2_w, wf2_t, 3072, 768);

  hipMemcpyAsync(xb, x_in, (size_t)ROWS * DMODEL * 4, hipMemcpyDeviceToDevice,
                 stream);

  for (int i = 0; i < DEPTH; ++i) {
    // attention block
    ln_kernel<<<ROWS, 256, 0, stream>>>(xb, ln1_g + i * 768, ln1_b + i * 768,
                                        hb, 0);
    gemm_bt<2, 2, 0><<<dim3(32, 36), 256, 0, stream>>>(
        hb, wq_t + (size_t)i * 2304 * 768, 768, 768, 768, qkvb, vt, nullptr);
    flash_attn<<<dim3(16, HEADS, BATCH), 256, 0, stream>>>(qkvb, vt, rel, ob);
    gemm_bt<1, 2, 3><<<dim3(64, 12), 256, 0, stream>>>(
        ob, wo_t + (size_t)i * 768 * 768, 768, 768, 768, xb, nullptr,
        out_b + i * 768);
    // FFN block
    ln_kernel<<<ROWS, 256, 0, stream>>>(xb, ln2_g + i * 768, ln2_b + i * 768,
                                        hb, 0);
    gemm_bt<2, 2, 4><<<dim3(32, 48), 256, 0, stream>>>(
        hb, wf1_t + (size_t)i * 3072 * 768, 768, 768, 768, ffb, nullptr,
        ff1_b + i * 3072);
    gemm_bt<1, 2, 5><<<dim3(64, 12), 256, 0, stream>>>(
        ffb, wf2_t + (size_t)i * 768 * 3072, 3072, 3072, 3072, xb, nullptr,
        ff2_b + i * 768);
    if (i == 2)
      feat_kernel<<<dim3(32, 24, 2), tb, 0, stream>>>(xb, out + 1572864);
    if (i == 5)
      feat_kernel<<<dim3(32, 24, 2), tb, 0, stream>>>(xb, out + 2 * 1572864);
  }
  ln_kernel<<<ROWS, 256, 0, stream>>>(xb, lnf_g, lnf_b, out, 1);
}

// Round 8
// 913.383 us; speedup vs baseline: 1.2092x; 1.0152x over previous
//
#include <hip/hip_runtime.h>
#include <hip/hip_bf16.h>

typedef unsigned short ushort_t;
typedef __attribute__((ext_vector_type(8))) __bf16 bf16x8;
typedef __attribute__((ext_vector_type(8))) unsigned short u16x8;
typedef __attribute__((ext_vector_type(4))) float f32x4;
typedef __attribute__((ext_vector_type(4))) unsigned int u32x4;

#define DEPTH 6
#define HEADS 12
#define DMODEL 768
#define FFDIM 3072
#define BATCH 2
#define SEQ 1024
#define ROWS (BATCH * SEQ)

static __device__ __forceinline__ ushort_t f2bf(float f) {
  unsigned u = __builtin_bit_cast(unsigned, f);
  u += 0x7fffu + ((u >> 16) & 1u);
  return (ushort_t)(u >> 16);
}
static __device__ __forceinline__ float bf2f(ushort_t v) {
  return __builtin_bit_cast(float, (unsigned)v << 16);
}

// ---------------------------------------------------------------------------
// GEMM: C[M,N] = A[M,K] @ Bt[N,K]^T, bf16 K-major, fp32 MFMA accum.
// 2-phase double-buffered, small tiles for TLP (round-7 best structure).
// LDS linear dest + XOR-swizzled global source; swizzled ds_read_b128.
// XCD-aware bijective block swizzle (all grids divisible by 8).
// EPI: 0=qkv(q,k->qkvb, v->vt), 3=out-proj residual RMW,
//      4=ff1 bias+gelu bf16, 5=ff2 residual RMW
// ---------------------------------------------------------------------------
template <int MREP, int NREP, int EPI>
__global__ __launch_bounds__(256) void gemm_bt(
    const ushort_t* __restrict__ A, const ushort_t* __restrict__ Bt,
    int lda, int ldb, int K,
    void* __restrict__ out0, void* __restrict__ out1,
    const float* __restrict__ f0) {
  constexpr int BM = 32 * MREP;
  constexpr int BN = 32 * NREP;
  constexpr int CHA = BM / 32;  // 8-row staging chunks per wave
  constexpr int CHB = BN / 32;
  __shared__ ushort_t sA[2][BM * 64];
  __shared__ ushort_t sB[2][BN * 64];

  const int tid = threadIdx.x;
  const int lane = tid & 63;
  const int wid = tid >> 6;
  const int wm = wid >> 1, wn = wid & 1;

  // XCD-aware bijective block swizzle (total blocks divisible by 8)
  int bx, by;
  {
    const int nb = gridDim.x * gridDim.y;
    const int bid = blockIdx.y * gridDim.x + blockIdx.x;
    const int q = nb >> 3;
    const int swz = (bid & 7) * q + (bid >> 3);
    bx = swz % gridDim.x;
    by = swz / gridDim.x;
  }

  const ushort_t* Ab = A + (long)bx * BM * lda;
  const ushort_t* Bb = Bt + (long)by * BN * ldb;

  const int srow = lane >> 3;                // row within 8-row chunk
  const int scol = ((lane & 7) ^ srow) * 8;  // swizzled source col (elems)

  f32x4 acc[MREP][NREP];
#pragma unroll
  for (int m = 0; m < MREP; ++m)
#pragma unroll
    for (int n = 0; n < NREP; ++n) acc[m][n] = (f32x4){0.f, 0.f, 0.f, 0.f};

  const int fr = lane & 15;
  const int kq4 = lane >> 4;

  auto stage_tile = [&](int buf, int t) {
    const int k0 = t * 64;
#pragma unroll
    for (int j = 0; j < CHA; ++j) {
      const int c = wid * CHA + j;
      const ushort_t* src = Ab + (long)(c * 8 + srow) * lda + k0 + scol;
      __builtin_amdgcn_global_load_lds(
          (const __attribute__((address_space(1))) void*)src,
          (__attribute__((address_space(3))) void*)&sA[buf][c * 512], 16, 0, 0);
    }
#pragma unroll
    for (int j = 0; j < CHB; ++j) {
      const int c = wid * CHB + j;
      const ushort_t* src = Bb + (long)(c * 8 + srow) * ldb + k0 + scol;
      __builtin_amdgcn_global_load_lds(
          (const __attribute__((address_space(1))) void*)src,
          (__attribute__((address_space(3))) void*)&sB[buf][c * 512], 16, 0, 0);
    }
  };

  const int nt = K / 64;
  stage_tile(0, 0);
  for (int t = 0; t < nt; ++t) {
    const int cur = t & 1;
    asm volatile("s_waitcnt vmcnt(0)" ::: "memory");
    __builtin_amdgcn_s_barrier();
    if (t + 1 < nt) stage_tile(cur ^ 1, t + 1);
#pragma unroll
    for (int kk = 0; kk < 2; ++kk) {
      bf16x8 af[MREP], bfr[NREP];
#pragma unroll
      for (int m = 0; m < MREP; ++m) {
        const int row = wm * (MREP * 16) + m * 16 + fr;
        const int ch = (kk * 4 + kq4) ^ (row & 7);
        af[m] = *(const bf16x8*)&sA[cur][row * 64 + ch * 8];
      }
#pragma unroll
      for (int n = 0; n < NREP; ++n) {
        const int row = wn * (NREP * 16) + n * 16 + fr;
        const int ch = (kk * 4 + kq4) ^ (row & 7);
        bfr[n] = *(const bf16x8*)&sB[cur][row * 64 + ch * 8];
      }
#pragma unroll
      for (int m = 0; m < MREP; ++m)
#pragma unroll
        for (int n = 0; n < NREP; ++n)
          acc[m][n] = __builtin_amdgcn_mfma_f32_16x16x32_bf16(
              af[m], bfr[n], acc[m][n], 0, 0, 0);
    }
  }

  const long grow0 = (long)bx * BM + wm * (MREP * 16);
  const long gcol0 = (long)by * BN + wn * (NREP * 16);
  const int rr = (lane >> 4) * 4;
  const int cc = lane & 15;

#pragma unroll
  for (int m = 0; m < MREP; ++m) {
#pragma unroll
    for (int n = 0; n < NREP; ++n) {
#pragma unroll
      for (int r = 0; r < 4; ++r) {
        long row = grow0 + m * 16 + rr + r;
        long col = gcol0 + n * 16 + cc;
        float c = acc[m][n][r];
        if (EPI == 0) {
          ushort_t bv = f2bf(c);
          if (col < 1536) {
            ((ushort_t*)out0)[row * 2304 + col] = bv;
          } else {  // V block -> V^T only
            long h = (col - 1536) >> 6, d = (col - 1536) & 63;
            long b = row >> 10, i = row & 1023;
            ((ushort_t*)out1)[(((b * HEADS) + h) * 64 + d) * 1024 + i] = bv;
          }
        } else if (EPI == 3) {
          long idx = row * DMODEL + col;
          ((float*)out0)[idx] += c + f0[col];
        } else if (EPI == 4) {
          float t = c + f0[col];
          float g = 0.5f * t * (1.0f + erff(t * 0.70710678118f));
          ((ushort_t*)out0)[row * FFDIM + col] = f2bf(g);
        } else if (EPI == 5) {
          long idx = row * DMODEL + col;
          ((float*)out0)[idx] += c + f0[col];
        }
      }
    }
  }
}

// ---------------------------------------------------------------------------
// pack_bias: rel[h][q][k] fp32 -> pbias[h][qi][t][lane][16] bf16, the exact
// per-lane fragment layout flash consumes (lane=(kq4*16+cc), idx=n*4+r,
// q=qi*16+kq4*4+r, k=t*64+n*16+cc). One block per (h,qi,t) 16x64 tile:
// coalesced fp32 read -> LDS scatter -> coalesced bf16 write.
// ---------------------------------------------------------------------------
__global__ __launch_bounds__(256) void pack_bias(const float* __restrict__ rel,
                                                 ushort_t* __restrict__ pb) {
  __shared__ ushort_t tile[1024];
  const int blk = blockIdx.x;  // (h*64+qi)*16 + t
  const int t = blk & 15, qi = (blk >> 4) & 63, h = blk >> 10;
  const float* src = rel + ((size_t)h << 20) + (size_t)(qi * 16) * 1024 + t * 64;
  const int tid = threadIdx.x;
  const int kk = tid & 63;
#pragma unroll
  for (int it = 0; it < 4; ++it) {
    const int qr = (tid >> 6) * 4 + it;
    const float v = src[(size_t)qr * 1024 + kk];
    const int lane = (qr >> 2) * 16 + (kk & 15);
    const int idx = (kk >> 4) * 4 + (qr & 3);
    tile[lane * 16 + idx] = f2bf(v);
  }
  __syncthreads();
  ushort_t* dst = pb + (size_t)blk * 1024;
#pragma unroll
  for (int it = 0; it < 4; ++it) dst[it * 256 + tid] = tile[it * 256 + tid];
}

// ---------------------------------------------------------------------------
// Flash attention: QBLK=32, KVBLK=64, 128 threads (2 waves), each wave owns
// 16 q-rows. Q in regs (A-frag). K/V double-buffered swizzled LDS. Bias from
// pre-packed bf16 fragments, PREFETCHED one tile ahead (named regs, 2-step
// unrolled loop -> no runtime reg indexing). P via swizzled LDS.
// grid: (SEQ/32, HEADS, BATCH), 768 blocks.
// ---------------------------------------------------------------------------
__global__ __launch_bounds__(128) void flash_attn(
    const ushort_t* __restrict__ qkv,   // [ROWS][2304]
    const ushort_t* __restrict__ vt,    // [B*H*64][1024] V^T
    const ushort_t* __restrict__ pbias, // packed [H][64][16][1024]
    ushort_t* __restrict__ o) {         // [ROWS][768]
  __shared__ ushort_t sK[2][64 * 64];
  __shared__ ushort_t sV[2][64 * 64];
  __shared__ ushort_t sP[32 * 64];

  const int tid = threadIdx.x;
  const int lane = tid & 63;
  const int wid = tid >> 6;  // 0..1
  const int h = blockIdx.y, b = blockIdx.z;
  const int q0 = blockIdx.x * 32;
  const int qi = blockIdx.x * 2 + wid;  // 16-row block index

  const int fr = lane & 15;
  const int kq4 = lane >> 4;
  const int rr = kq4 * 4;
  const int cc = fr;

  const int srow = lane >> 3;
  const int scol = ((lane & 7) ^ srow) * 8;

  const ushort_t* qbase =
      qkv + (size_t)(b * 1024 + q0 + wid * 16 + fr) * 2304 + h * 64;
  bf16x8 qreg[2];
  qreg[0] = *(const bf16x8*)&qbase[kq4 * 8];
  qreg[1] = *(const bf16x8*)&qbase[32 + kq4 * 8];

  const ushort_t* Kbase = qkv + (size_t)(b * 1024) * 2304 + 768 + h * 64;
  const ushort_t* Vbase = vt + (size_t)((b * HEADS + h) * 64) * 1024;
  const ushort_t* pbb = pbias + (((size_t)h * 64 + qi) << 14) + lane * 16;

  f32x4 acc_o[4];
  float m_run[4], l_run[4];
#pragma unroll
  for (int n = 0; n < 4; ++n) acc_o[n] = (f32x4){0.f, 0.f, 0.f, 0.f};
#pragma unroll
  for (int r = 0; r < 4; ++r) { m_run[r] = -1e30f; l_run[r] = 0.f; }

  auto stage_kv = [&](int buf, int t) {
#pragma unroll
    for (int j = 0; j < 4; ++j) {
      const int c = wid * 4 + j;
      const ushort_t* src = Kbase + (size_t)(t * 64 + c * 8 + srow) * 2304 + scol;
      __builtin_amdgcn_global_load_lds(
          (const __attribute__((address_space(1))) void*)src,
          (__attribute__((address_space(3))) void*)&sK[buf][c * 512], 16, 0, 0);
    }
#pragma unroll
    for (int j = 0; j < 4; ++j) {
      const int c = wid * 4 + j;
      const ushort_t* src = Vbase + (size_t)(c * 8 + srow) * 1024 + t * 64 + scol;
      __builtin_amdgcn_global_load_lds(
          (const __attribute__((address_space(1))) void*)src,
          (__attribute__((address_space(3))) void*)&sV[buf][c * 512], 16, 0, 0);
    }
  };

  auto step = [&](int t, u16x8& bc0, u16x8& bc1, u16x8& bn0, u16x8& bn1) {
    const int cur = t & 1;
    asm volatile("s_waitcnt vmcnt(0)" ::: "memory");
    __builtin_amdgcn_s_barrier();
    if (t + 1 < 16) {
      stage_kv(cur ^ 1, t + 1);
      const ushort_t* pp = pbb + (size_t)(t + 1) * 1024;
      bn0 = *(const u16x8*)pp;
      bn1 = *(const u16x8*)(pp + 8);
    }

    // S = Q @ K^T
    f32x4 s[4];
#pragma unroll
    for (int n = 0; n < 4; ++n) s[n] = (f32x4){0.f, 0.f, 0.f, 0.f};
#pragma unroll
    for (int kk = 0; kk < 2; ++kk) {
#pragma unroll
      for (int n = 0; n < 4; ++n) {
        const int row = n * 16 + fr;
        const int ch = (kk * 4 + kq4) ^ (row & 7);
        bf16x8 kf = *(const bf16x8*)&sK[cur][row * 64 + ch * 8];
        s[n] =
            __builtin_amdgcn_mfma_f32_16x16x32_bf16(qreg[kk], kf, s[n], 0, 0, 0);
      }
    }

    // scale + packed-bias add, per-row tile max
    float mr[4];
#pragma unroll
    for (int r = 0; r < 4; ++r) mr[r] = -1e30f;
#pragma unroll
    for (int n = 0; n < 4; ++n)
#pragma unroll
      for (int r = 0; r < 4; ++r) {
        const int idx = n * 4 + r;
        const float bv = bf2f(idx < 8 ? bc0[idx] : bc1[idx - 8]);
        float v = s[n][r] * 0.125f + bv;
        s[n][r] = v;
        mr[r] = fmaxf(mr[r], v);
      }
#pragma unroll
    for (int o_ = 1; o_ < 16; o_ <<= 1)
#pragma unroll
      for (int r = 0; r < 4; ++r) mr[r] = fmaxf(mr[r], __shfl_xor(mr[r], o_));

    float escale[4], psum[4];
#pragma unroll
    for (int r = 0; r < 4; ++r) {
      float mn = fmaxf(m_run[r], mr[r]);
      escale[r] = __expf(m_run[r] - mn);
      m_run[r] = mn;
      psum[r] = 0.f;
    }
#pragma unroll
    for (int n = 0; n < 4; ++n)
#pragma unroll
      for (int r = 0; r < 4; ++r) {
        float p = __expf(s[n][r] - m_run[r]);
        psum[r] += p;
        const int prow = wid * 16 + rr + r;
        const int pcol = n * 16 + cc;
        sP[prow * 64 + (((pcol >> 3) ^ (prow & 7)) << 3) + (pcol & 7)] = f2bf(p);
      }
#pragma unroll
    for (int o_ = 1; o_ < 16; o_ <<= 1)
#pragma unroll
      for (int r = 0; r < 4; ++r) psum[r] += __shfl_xor(psum[r], o_);
#pragma unroll
    for (int r = 0; r < 4; ++r) l_run[r] = l_run[r] * escale[r] + psum[r];

    asm volatile("s_waitcnt lgkmcnt(0)" ::: "memory");
    __builtin_amdgcn_s_barrier();

    // O = O*escale + P @ V
#pragma unroll
    for (int n = 0; n < 4; ++n)
#pragma unroll
      for (int r = 0; r < 4; ++r) acc_o[n][r] *= escale[r];
#pragma unroll
    for (int kk = 0; kk < 2; ++kk) {
      const int prow = wid * 16 + fr;
      const int pch = (kk * 4 + kq4) ^ (prow & 7);
      bf16x8 pf = *(const bf16x8*)&sP[prow * 64 + pch * 8];
#pragma unroll
      for (int n = 0; n < 4; ++n) {
        const int vrow = n * 16 + fr;
        const int vch = (kk * 4 + kq4) ^ (vrow & 7);
        bf16x8 vf = *(const bf16x8*)&sV[cur][vrow * 64 + vch * 8];
        acc_o[n] =
            __builtin_amdgcn_mfma_f32_16x16x32_bf16(pf, vf, acc_o[n], 0, 0, 0);
      }
    }
  };

  u16x8 bA0, bA1, bB0, bB1;
  bA0 = *(const u16x8*)pbb;
  bA1 = *(const u16x8*)(pbb + 8);
  stage_kv(0, 0);
  for (int tt = 0; tt < 16; tt += 2) {
    step(tt, bA0, bA1, bB0, bB1);
    step(tt + 1, bB0, bB1, bA0, bA1);
  }

  ushort_t* ob = o + (size_t)(b * 1024 + q0 + wid * 16) * 768 + h * 64;
#pragma unroll
  for (int r = 0; r < 4; ++r) {
    const float rinv = 1.f / l_run[r];
#pragma unroll
    for (int n = 0; n < 4; ++n)
      ob[(size_t)(rr + r) * 768 + n * 16 + cc] = f2bf(acc_o[n][r] * rinv);
  }
}

// ---------------------------------------------------------------------------
// Transpose + cast fp32 [R,C] -> bf16 [C,R], per-layer via blockIdx.z
// ---------------------------------------------------------------------------
__global__ __launch_bounds__(256) void transpose_cast(
    const float* __restrict__ in, ushort_t* __restrict__ out, int R, int C) {
  __shared__ float t[32][33];
  const float* ip = in + (long)blockIdx.z * R * C;
  ushort_t* op = out + (long)blockIdx.z * R * C;
  int c0 = blockIdx.x * 32, r0 = blockIdx.y * 32;
  int tx = threadIdx.x;
  for (int i = threadIdx.y; i < 32; i += 8)
    t[i][tx] = ip[(long)(r0 + i) * C + c0 + tx];
  __syncthreads();
  for (int i = threadIdx.y; i < 32; i += 8)
    op[(long)(c0 + i) * R + r0 + tx] = f2bf(t[tx][i]);
}

// ---------------------------------------------------------------------------
// LayerNorm over D=768; block per row; out bf16 (flag=0) or fp32 (flag=1)
// ---------------------------------------------------------------------------
__global__ __launch_bounds__(256) void ln_kernel(
    const float* __restrict__ x, const float* __restrict__ g,
    const float* __restrict__ b, void* __restrict__ out, int out_f32) {
  int row = blockIdx.x;
  int tid = threadIdx.x;
  int lane = tid & 63, wid = tid >> 6;
  const float* xr = x + (long)row * DMODEL;
  float v0 = xr[tid], v1 = xr[tid + 256], v2 = xr[tid + 512];
  float s = v0 + v1 + v2;
  __shared__ float red[8];
  for (int o = 32; o; o >>= 1) s += __shfl_xor(s, o);
  if (!lane) red[wid] = s;
  __syncthreads();
  float mean = (red[0] + red[1] + red[2] + red[3]) * (1.f / 768.f);
  float d0 = v0 - mean, d1 = v1 - mean, d2 = v2 - mean;
  float q = d0 * d0 + d1 * d1 + d2 * d2;
  for (int o = 32; o; o >>= 1) q += __shfl_xor(q, o);
  if (!lane) red[4 + wid] = q;
  __syncthreads();
  float var = (red[4] + red[5] + red[6] + red[7]) * (1.f / 768.f);
  float rs = rsqrtf(var + 1e-5f);
  float y0 = d0 * rs * g[tid] + b[tid];
  float y1 = d1 * rs * g[tid + 256] + b[tid + 256];
  float y2 = d2 * rs * g[tid + 512] + b[tid + 512];
  if (out_f32) {
    float* o_ = (float*)out + (long)row * DMODEL;
    o_[tid] = y0; o_[tid + 256] = y1; o_[tid + 512] = y2;
  } else {
    ushort_t* o_ = (ushort_t*)out + (long)row * DMODEL;
    o_[tid] = f2bf(y0); o_[tid + 256] = f2bf(y1); o_[tid + 512] = f2bf(y2);
  }
}

// ---------------------------------------------------------------------------
// Feature output: out[b, c, n] = x[b, n, c]
// ---------------------------------------------------------------------------
__global__ __launch_bounds__(256) void feat_kernel(const float* __restrict__ x,
                                                   float* __restrict__ out) {
  __shared__ float t[32][33];
  const float* xp = x + (long)blockIdx.z * SEQ * DMODEL;
  float* op = out + (long)blockIdx.z * DMODEL * SEQ;
  int n0 = blockIdx.x * 32, c0 = blockIdx.y * 32;
  int tx = threadIdx.x;
  for (int i = threadIdx.y; i < 32; i += 8)
    t[i][tx] = xp[(long)(n0 + i) * DMODEL + c0 + tx];
  __syncthreads();
  for (int i = threadIdx.y; i < 32; i += 8)
    op[(long)(c0 + i) * SEQ + n0 + tx] = t[tx][i];
}

// ---------------------------------------------------------------------------
extern "C" void kernel_launch(void* const* d_in, const int* in_sizes, int n_in,
                              void* d_out, int out_size, void* d_ws,
                              size_t ws_size, hipStream_t stream) {
  const float* x_in   = (const float*)d_in[0];
  const float* rel    = (const float*)d_in[1];
  const float* ln1_g  = (const float*)d_in[2];
  const float* ln1_b  = (const float*)d_in[3];
  const float* qkv_w  = (const float*)d_in[4];
  const float* out_w  = (const float*)d_in[5];
  const float* out_b  = (const float*)d_in[6];
  const float* ln2_g  = (const float*)d_in[7];
  const float* ln2_b  = (const float*)d_in[8];
  const float* ff1_w  = (const float*)d_in[9];
  const float* ff1_b  = (const float*)d_in[10];
  const float* ff2_w  = (const float*)d_in[11];
  const float* ff2_b  = (const float*)d_in[12];
  const float* lnf_g  = (const float*)d_in[13];
  const float* lnf_b  = (const float*)d_in[14];
  float* out = (float*)d_out;

  char* w = (char*)d_ws;
  ushort_t* wq_t = (ushort_t*)w; w += (size_t)DEPTH * 2304 * 768 * 2;
  ushort_t* wo_t = (ushort_t*)w; w += (size_t)DEPTH * 768 * 768 * 2;
  ushort_t* wf1_t = (ushort_t*)w; w += (size_t)DEPTH * 3072 * 768 * 2;
  ushort_t* wf2_t = (ushort_t*)w; w += (size_t)DEPTH * 768 * 3072 * 2;
  float* xb = (float*)w; w += (size_t)ROWS * DMODEL * 4;
  ushort_t* hb = (ushort_t*)w; w += (size_t)ROWS * DMODEL * 2;
  ushort_t* qkvb = (ushort_t*)w; w += (size_t)ROWS * 2304 * 2;
  ushort_t* vt = (ushort_t*)w; w += (size_t)BATCH * HEADS * 64 * 1024 * 2;
  ushort_t* ob = (ushort_t*)w; w += (size_t)ROWS * DMODEL * 2;
  ushort_t* ffb = (ushort_t*)w; w += (size_t)ROWS * FFDIM * 2;
  ushort_t* pbias = (ushort_t*)w; w += (size_t)HEADS * 1024 * 1024 * 2;

  dim3 tb(32, 8);
  // weight prep: fp32 [K,N] -> bf16 [N,K]
  transpose_cast<<<dim3(2304 / 32, 768 / 32, DEPTH), tb, 0, stream>>>(
      qkv_w, wq_t, 768, 2304);
  transpose_cast<<<dim3(768 / 32, 768 / 32, DEPTH), tb, 0, stream>>>(
      out_w, wo_t, 768, 768);
  transpose_cast<<<dim3(3072 / 32, 768 / 32, DEPTH), tb, 0, stream>>>(
      ff1_w, wf1_t, 768, 3072);
  transpose_cast<<<dim3(768 / 32, 3072 / 32, DEPTH), tb, 0, stream>>>(
      ff2_w, wf2_t, 3072, 768);
  pack_bias<<<HEADS * 64 * 16, 256, 0, stream>>>(rel, pbias);

  hipMemcpyAsync(xb, x_in, (size_t)ROWS * DMODEL * 4, hipMemcpyDeviceToDevice,
                 stream);

  for (int i = 0; i < DEPTH; ++i) {
    // attention block
    ln_kernel<<<ROWS, 256, 0, stream>>>(xb, ln1_g + i * 768, ln1_b + i * 768,
                                        hb, 0);
    gemm_bt<2, 2, 0><<<dim3(32, 36), 256, 0, stream>>>(
        hb, wq_t + (size_t)i * 2304 * 768, 768, 768, 768, qkvb, vt, nullptr);
    flash_attn<<<dim3(32, HEADS, BATCH), 128, 0, stream>>>(qkvb, vt, pbias, ob);
    gemm_bt<1, 2, 3><<<dim3(64, 12), 256, 0, stream>>>(
        ob, wo_t + (size_t)i * 768 * 768, 768, 768, 768, xb, nullptr,
        out_b + i * 768);
    // FFN block
    ln_kernel<<<ROWS, 256, 0, stream>>>(xb, ln2_g + i * 768, ln2_b + i * 768,
                                        hb, 0);
    gemm_bt<2, 2, 4><<<dim3(32, 48), 256, 0, stream>>>(
        hb, wf1_t + (size_t)i * 3072 * 768, 768, 768, 768, ffb, nullptr,
        ff1_b + i * 3072);
    gemm_bt<1, 2, 5><<<dim3(64, 12), 256, 0, stream>>>(
        ffb, wf2_t + (size_t)i * 768 * 3072, 3072, 3072, 3072, xb, nullptr,
        ff2_b + i * 768);
    if (i == 2)
      feat_kernel<<<dim3(32, 24, 2), tb, 0, stream>>>(xb, out + 1572864);
    if (i == 5)
      feat_kernel<<<dim3(32, 24, 2), tb, 0, stream>>>(xb, out + 2 * 1572864);
  }
  ln_kernel<<<ROWS, 256, 0, stream>>>(xb, lnf_g, lnf_b, out, 1);
}